// Round 4
// baseline (929.592 us; speedup 1.0000x reference)
//
#include <hip/hip_runtime.h>
#include <hip/hip_fp16.h>
#include <math.h>

#define R2 2500.0f
#define EPSF 1e-8f

constexpr int H  = 256;   // feature dim (fixed by problem)
constexpr int HH = 128;   // hidden dim

// ---------------- K1: degree count ----------------
__global__ void k_degree(const int* __restrict__ row, int* __restrict__ deg, int E) {
    int e = blockIdx.x * blockDim.x + threadIdx.x;
    if (e < E) atomicAdd(&deg[row[e]], 1);
}

// ---------------- K2: exclusive scan (single block, 1024 thr) ----------------
__global__ void k_scan(const int* __restrict__ deg, int* __restrict__ row_ptr, int N) {
    __shared__ int s[1024];
    int t = threadIdx.x;
    int per = N >> 10;            // N/1024 (N=16384 -> 16)
    int base = t * per;
    int vals[32];
    int local = 0;
    for (int k = 0; k < per; k++) { vals[k] = deg[base + k]; local += vals[k]; }
    s[t] = local;
    __syncthreads();
    for (int off = 1; off < 1024; off <<= 1) {
        int v = s[t];
        int add = (t >= off) ? s[t - off] : 0;
        __syncthreads();
        s[t] = v + add;
        __syncthreads();
    }
    int excl = (t > 0) ? s[t - 1] : 0;
    for (int k = 0; k < per; k++) { row_ptr[base + k] = excl; excl += vals[k]; }
    if (t == 1023) row_ptr[N] = excl;
}

// ---------------- K3: CSR fill ----------------
__global__ void k_fill(const int* __restrict__ row, const int* __restrict__ col,
                       const int* __restrict__ row_ptr, int* __restrict__ fill,
                       int* __restrict__ cols, int E) {
    int e = blockIdx.x * blockDim.x + threadIdx.x;
    if (e < E) {
        int r = row[e];
        int p = row_ptr[r] + atomicAdd(&fill[r], 1);
        cols[p] = col[e];
    }
}

// ---------------- K3b: x -> fp16 copy (halves gather bytes) ----------------
__global__ void k_half(const float* __restrict__ x, unsigned short* __restrict__ xh,
                       int total4) {
    int t = blockIdx.x * blockDim.x + threadIdx.x;
    if (t < total4) {
        float4 v = ((const float4*)x)[t];
        __half2 a = __floats2half2_rn(v.x, v.y);
        __half2 b = __floats2half2_rn(v.z, v.w);
        uint2 r;
        r.x = __builtin_bit_cast(unsigned int, a);
        r.y = __builtin_bit_cast(unsigned int, b);
        ((uint2*)xh)[t] = r;
    }
}

// ---------------- K4: spatial density (pairwise count) ----------------
__global__ void k_density(const float* __restrict__ coords, int* __restrict__ dens,
                          int N, int jPer) {
    __shared__ float sx[256], sy[256], sq[256];
    int i = blockIdx.x * 256 + threadIdx.x;
    const float2* c2 = (const float2*)coords;
    float2 ci = c2[i];
    float sqi = ci.x * ci.x + ci.y * ci.y;
    int j0 = blockIdx.y * jPer;
    int cnt = 0;
    for (int jt = j0; jt < j0 + jPer; jt += 256) {
        float2 cj = c2[jt + threadIdx.x];
        sx[threadIdx.x] = cj.x;
        sy[threadIdx.x] = cj.y;
        sq[threadIdx.x] = cj.x * cj.x + cj.y * cj.y;
        __syncthreads();
#pragma unroll 8
        for (int k = 0; k < 256; k++) {
            float dot = ci.x * sx[k] + ci.y * sy[k];
            float d2 = (sqi + sq[k]) - 2.0f * dot;
            cnt += (d2 <= R2) ? 1 : 0;
        }
        __syncthreads();
    }
    atomicAdd(&dens[i], cnt);
}

// ---------------- K5: fvar, L2-resident col-sliced gather ----------------
// One wave owns 8 nodes (8 float4 accumulators in VGPRs). Neighbor
// accumulation runs in NPASS passes over col-ranges; each pass's fp16 x
// slice (2MB) fits every XCD's 4MB L2, so after first touch the random
// row-gathers are L2 hits. Pass-major order keeps the whole device on the
// same slice at the same time.
__global__ void __launch_bounds__(256) k_fvar(
    const float* __restrict__ x, const unsigned short* __restrict__ xh,
    const int* __restrict__ row_ptr, const int* __restrict__ cols,
    const int* __restrict__ dens, float* __restrict__ fvar,
    int* __restrict__ scal, int N) {
    constexpr int NPASS = 4;
    const int SLICE = N / NPASS;           // 4096 nodes = 2MB fp16
    int wave = threadIdx.x >> 6;
    int lane = threadIdx.x & 63;
    int wid = blockIdx.x * 4 + wave;       // grid = N/32 blocks, 4 waves each
    int n0 = wid * 8;                      // first of this wave's 8 nodes

    float4 a0 = {0,0,0,0}, a1 = {0,0,0,0}, a2 = {0,0,0,0}, a3 = {0,0,0,0};
    float4 a4 = {0,0,0,0}, a5 = {0,0,0,0}, a6 = {0,0,0,0}, a7 = {0,0,0,0};

    const uint2* xhb = (const uint2*)xh;   // 64 lanes x 8B per row

    auto accum_node = [&](int i, int lo, int hi, float4& acc) {
        int s = row_ptr[i], e = row_ptr[i + 1];
        for (int q0 = s; q0 < e; q0 += 64) {
            int m = e - q0; if (m > 64) m = 64;
            int idx = cols[q0 + (lane < m ? lane : 0)];
            for (int j = 0; j < m; j++) {
                int c = __shfl(idx, j, 64);       // wave-uniform -> no divergence
                if (c >= lo && c < hi) {
                    uint2 r = xhb[(size_t)c * 64 + lane];
                    __half2 ha = __builtin_bit_cast(__half2, r.x);
                    __half2 hb = __builtin_bit_cast(__half2, r.y);
                    float2 fa = __half22float2(ha);
                    float2 fb = __half22float2(hb);
                    acc.x += fa.x; acc.y += fa.y; acc.z += fb.x; acc.w += fb.y;
                }
            }
        }
    };

    for (int p = 0; p < NPASS; p++) {
        int lo = p * SLICE, hi = lo + SLICE;
        accum_node(n0 + 0, lo, hi, a0);
        accum_node(n0 + 1, lo, hi, a1);
        accum_node(n0 + 2, lo, hi, a2);
        accum_node(n0 + 3, lo, hi, a3);
        accum_node(n0 + 4, lo, hi, a4);
        accum_node(n0 + 5, lo, hi, a5);
        accum_node(n0 + 6, lo, hi, a6);
        accum_node(n0 + 7, lo, hi, a7);
    }

    const float4* xb = (const float4*)x;
    float4 accs[8] = {a0, a1, a2, a3, a4, a5, a6, a7};
#pragma unroll
    for (int n = 0; n < 8; n++) {
        int i = n0 + n;
        int degi = row_ptr[i + 1] - row_ptr[i];
        float cnt = fmaxf((float)degi, 1.0f);
        float4 xi = xb[(size_t)i * 64 + lane];
        float dx = xi.x - accs[n].x / cnt;
        float dy = xi.y - accs[n].y / cnt;
        float dz = xi.z - accs[n].z / cnt;
        float dw = xi.w - accs[n].w / cnt;
        float ss = dx * dx + dy * dy + dz * dz + dw * dw;
#pragma unroll
        for (int off = 32; off > 0; off >>= 1) ss += __shfl_xor(ss, off, 64);
        if (lane == 0) {
            float fv = sqrtf(ss);
            fvar[i] = fv;
            atomicMax(&scal[0], degi);                   // max degree
            atomicMax(&scal[1], dens[i]);                // max raw density count
            atomicMax(&scal[2], __float_as_int(fv));     // max fvar
        }
    }
}

// ---------------- K6: tiny MLP ----------------
__global__ void __launch_bounds__(256) k_mlp(
    const float* __restrict__ w1, const float* __restrict__ b1,
    const float* __restrict__ w2, const float* __restrict__ b2,
    const int* __restrict__ deg, const int* __restrict__ dens,
    const float* __restrict__ fvar, const int* __restrict__ scal,
    float* __restrict__ out, int N) {
    __shared__ float sh_h[HH];
    int j = threadIdx.x;
    float wv[HH];
#pragma unroll
    for (int l = 0; l < HH; l++) wv[l] = w2[l * H + j];
    float bj = b2[j];
    float maxdeg  = (float)scal[0] + EPSF;
    float maxdens = (float)(scal[1] - 1) + EPSF;
    float maxfv   = __int_as_float(scal[2]) + EPSF;
    float w1a = 0.f, w1b = 0.f, w1c = 0.f, b1j = 0.f;
    if (j < HH) { w1a = w1[j]; w1b = w1[HH + j]; w1c = w1[2 * HH + j]; b1j = b1[j]; }
    for (int i = blockIdx.x; i < N; i += gridDim.x) {
        float f0 = (float)deg[i] / maxdeg;
        float f1 = (float)(dens[i] - 1) / maxdens;
        float f2 = fvar[i] / maxfv;
        if (j < HH) {
            float h = f0 * w1a + f1 * w1b + f2 * w1c + b1j;
            sh_h[j] = fmaxf(h, 0.0f);
        }
        __syncthreads();
        float acc = bj;
#pragma unroll
        for (int l = 0; l < HH; l++) acc = fmaf(sh_h[l], wv[l], acc);
        out[(size_t)i * H + j] = acc;
        __syncthreads();
    }
}

extern "C" void kernel_launch(void* const* d_in, const int* in_sizes, int n_in,
                              void* d_out, int out_size, void* d_ws, size_t ws_size,
                              hipStream_t stream) {
    const float* x      = (const float*)d_in[0];
    const int*   ei     = (const int*)d_in[1];
    const float* coords = (const float*)d_in[2];
    const float* w1     = (const float*)d_in[3];
    const float* b1     = (const float*)d_in[4];
    const float* w2     = (const float*)d_in[5];
    const float* b2     = (const float*)d_in[6];
    float* out = (float*)d_out;

    const int N = in_sizes[2] / 2;   // 16384
    const int E = in_sizes[1] / 2;   // 524288
    const int* row = ei;
    const int* col = ei + E;

    // workspace layout (int32 elements)
    int* ws       = (int*)d_ws;
    int* deg_cnt  = ws;                        // [N]   zeroed
    int* dens_cnt = ws + N;                    // [N]   zeroed
    int* fill     = ws + 2 * N;                // [N]   zeroed
    int* scal     = ws + 3 * N;                // [4]   zeroed
    float* fvarp  = (float*)(ws + 3 * N + 4);  // [N]
    int* row_ptr  = ws + 4 * N + 4;            // [N+1]
    int* cols     = ws + 5 * N + 5;            // [E]
    unsigned short* xh = (unsigned short*)(ws + 5 * N + 5 + E + 3); // [N*H] fp16, 8B-aligned

    hipMemsetAsync(ws, 0, (size_t)(3 * N + 4) * sizeof(int), stream);

    int eb = (E + 255) / 256;
    k_degree<<<eb, 256, 0, stream>>>(row, deg_cnt, E);
    k_scan<<<1, 1024, 0, stream>>>(deg_cnt, row_ptr, N);
    k_fill<<<eb, 256, 0, stream>>>(row, col, row_ptr, fill, cols, E);

    int t4 = N * (H / 4);
    k_half<<<(t4 + 255) / 256, 256, 0, stream>>>(x, xh, t4);

    const int NSLICE = 8;
    k_density<<<dim3(N / 256, NSLICE), 256, 0, stream>>>(coords, dens_cnt, N, N / NSLICE);

    k_fvar<<<N / 32, 256, 0, stream>>>(x, xh, row_ptr, cols, dens_cnt,
                                       fvarp, scal, N);

    k_mlp<<<1024, 256, 0, stream>>>(w1, b1, w2, b2, deg_cnt, dens_cnt, fvarp, scal,
                                    out, N);
}